// Round 2
// baseline (226.921 us; speedup 1.0000x reference)
//
#include <hip/hip_runtime.h>

// entmax-1.5 attention, round 8: barrier-free MFMA phases, direct
// global->register K/V fragments (no kv LDS staging at all).
// Insight: wave w's B-fragments use only K rows / V^T rows w*16..w*16+15 —
// no cross-wave reuse -> LDS staging was pure overhead + ~62 barriers.
// B=4 H=8 S=1024 D=128. Pre: K->bf16 [bh][key][d]; V->bf16 [bh][d][key].
// Main: 2048 blocks (32 bh x 64 q-tiles of 16 rows), 512 thr (8 waves).
// LDS = sc 32K + q_s 4K = 36,864 B -> 4 blocks/CU (32 waves = 100% cap),
// __launch_bounds__(512,8) pins VGPR <= 64. Exactly 3 barriers total.
// Phase 1: per wave, 8 key-tiles: 4 direct 16B K loads (depth-1 prefetch,
//          counted vmcnt) + 4 MFMA; scaled scores -> sc (bf16, swizzled).
// Phase 2: 32 thr/row regather+mask+max+normalize; full-register 14-iter
//          bisection (no compaction — handles all-masked rows too).
// Phase 3: O = P @ V^T, same direct-global fragment pattern for V^T;
//          ap fragments from swizzled sc; tile-0 V loads issued before the
//          barrier so latency hides under the barrier wait.

#define S_ 1024
#define D_ 128
#define NEG_INF_F (-1.0e12f)
#define SCALE_F 0.08838834764831845f  // 1/sqrt(128)
#define NITER 14                      // dTau=6e-5 -> out err ~1e-3 << 0.0766

typedef float f32x4 __attribute__((ext_vector_type(4)));
typedef short short8 __attribute__((ext_vector_type(8)));

__device__ __forceinline__ ushort f2bf(float x) {   // RNE f32 -> bf16
    unsigned u = __builtin_bit_cast(unsigned, x);
    u += 0x7FFFu + ((u >> 16) & 1u);
    return (ushort)(u >> 16);
}
__device__ __forceinline__ float bf2f(ushort h) {
    unsigned u = ((unsigned)h) << 16;
    return __builtin_bit_cast(float, u);
}

// ---- fused pre-kernel: blocks 0..4095 K->bf16; 4096..5119 V->bf16-T ----
__global__ __launch_bounds__(256)
void pre_cvt(const float* __restrict__ K, const float* __restrict__ V,
             ushort* __restrict__ Kb, ushort* __restrict__ Vt)
{
    __shared__ __align__(16) ushort tileT[64][68];  // [d][key], pad->8B rows
    const int t = threadIdx.x;
    if (blockIdx.x < 4096) {                        // K convert (coalesced)
        int i = blockIdx.x * 256 + t;               // 1,048,576 float4s
        float4 v = ((const float4*)K)[i];
        ushort4 o;
        o.x = f2bf(v.x); o.y = f2bf(v.y); o.z = f2bf(v.z); o.w = f2bf(v.w);
        ((ushort4*)Kb)[i] = o;
        return;
    }
    // V transpose: 64x64 tile per block. 1024 blocks = 32 bh x 16 kt x 2 dh
    const int vb = blockIdx.x - 4096;
    const int bh = vb >> 5, r5 = vb & 31, kt = r5 >> 1, dh = r5 & 1;
    const float* src = V + ((size_t)(bh * S_ + kt * 64)) * D_ + dh * 64;
    #pragma unroll
    for (int i = 0; i < 4; ++i) {                   // 1024 float4 loads
        int idx = t + i * 256, r = idx >> 4, c = idx & 15;
        float4 vv = *(const float4*)(src + (size_t)r * D_ + c * 4);
        tileT[c * 4 + 0][r] = f2bf(vv.x);           // scatter-transpose
        tileT[c * 4 + 1][r] = f2bf(vv.y);
        tileT[c * 4 + 2][r] = f2bf(vv.z);
        tileT[c * 4 + 3][r] = f2bf(vv.w);
    }
    __syncthreads();
    ushort* dst = Vt + ((size_t)(bh * D_ + dh * 64)) * S_ + kt * 64;
    #pragma unroll
    for (int i = 0; i < 2; ++i) {                   // contiguous reads/stores
        int idx = t + i * 256, d = idx >> 3, jj = idx & 7;
        short8 val = *(const short8*)&tileT[d][jj * 8];
        *(short8*)(dst + (size_t)d * S_ + jj * 8) = val;
    }
}

// ---- main kernel --------------------------------------------------------
__global__ __launch_bounds__(512, 8)
void entmax_attn(const float* __restrict__ Q, const ushort* __restrict__ Kb,
                 const ushort* __restrict__ Vt, const int* __restrict__ M,
                 float* __restrict__ O)
{
    __shared__ __align__(16) ushort sc[16][1024];   // scores/P bf16, swizzled
    __shared__ __align__(16) ushort q_s[16][128];   // Q tile bf16, swizzled

    const int t = threadIdx.x;
    const int w = t >> 6, lane = t & 63, l = lane & 15, quad = lane >> 4;
    const int bh = blockIdx.x >> 6, qt = blockIdx.x & 63, b = bh >> 3;

    const ushort* kb_bh = Kb + (size_t)bh * (S_ * D_);
    const ushort* vt_bh = Vt + (size_t)bh * (D_ * S_);

    // ---- stage Q tile (16x128 fp32 -> bf16, swizzled) ------------------
    {
        const float4* qsrc = (const float4*)(Q + ((size_t)bh * S_ + (size_t)qt * 16) * D_);
        int r = t >> 5, c = t & 31;
        float4 v = qsrc[r * 32 + c];
        ushort4 o;
        o.x = f2bf(v.x); o.y = f2bf(v.y); o.z = f2bf(v.z); o.w = f2bf(v.w);
        *(ushort4*)&q_s[r][(((c >> 1) ^ (r & 7)) << 3) + ((c & 1) << 2)] = o;
    }

    // K fragment base: key row = w*16+l, chunk = quad*8 (16B per fragment)
    const ushort* kp = kb_bh + (size_t)(w * 16 + l) * D_ + quad * 8;
    short8 c0 = *(const short8*)(kp +  0);          // tile 0, issued pre-bar
    short8 c1 = *(const short8*)(kp + 32);
    short8 c2 = *(const short8*)(kp + 64);
    short8 c3 = *(const short8*)(kp + 96);

    __syncthreads();                                // q_s visible

    short8 aq[4];                                   // A[m=l][k=ks*32+quad*8+e]
    #pragma unroll
    for (int ks = 0; ks < 4; ++ks)
        aq[ks] = *(const short8*)&q_s[l][((ks * 4 + quad) ^ (l & 7)) << 3];

    // ---- phase 1: QK^T, 8 key-tiles, barrier-free ----------------------
    #pragma unroll 1
    for (int kt = 0; kt < 7; ++kt) {
        const ushort* np = kp + (size_t)(kt + 1) * (128 * D_);
        short8 n0 = *(const short8*)(np +  0);      // prefetch next tile
        short8 n1 = *(const short8*)(np + 32);
        short8 n2 = *(const short8*)(np + 64);
        short8 n3 = *(const short8*)(np + 96);
        f32x4 acc = {0.f, 0.f, 0.f, 0.f};
        __builtin_amdgcn_s_setprio(1);
        acc = __builtin_amdgcn_mfma_f32_16x16x32_bf16(aq[0], c0, acc, 0, 0, 0);
        acc = __builtin_amdgcn_mfma_f32_16x16x32_bf16(aq[1], c1, acc, 0, 0, 0);
        acc = __builtin_amdgcn_mfma_f32_16x16x32_bf16(aq[2], c2, acc, 0, 0, 0);
        acc = __builtin_amdgcn_mfma_f32_16x16x32_bf16(aq[3], c3, acc, 0, 0, 0);
        __builtin_amdgcn_s_setprio(0);
        const int coln = kt * 16 + w * 2 + (l >> 3);    // col>>3
        #pragma unroll
        for (int r = 0; r < 4; ++r) {
            const int rr = quad * 4 + r;
            sc[rr][((coln ^ (rr & 7)) << 3) + (l & 7)] = f2bf(acc[r] * SCALE_F);
        }
        c0 = n0; c1 = n1; c2 = n2; c3 = n3;
    }
    {   // kt = 7 (peeled; no prefetch)
        f32x4 acc = {0.f, 0.f, 0.f, 0.f};
        __builtin_amdgcn_s_setprio(1);
        acc = __builtin_amdgcn_mfma_f32_16x16x32_bf16(aq[0], c0, acc, 0, 0, 0);
        acc = __builtin_amdgcn_mfma_f32_16x16x32_bf16(aq[1], c1, acc, 0, 0, 0);
        acc = __builtin_amdgcn_mfma_f32_16x16x32_bf16(aq[2], c2, acc, 0, 0, 0);
        acc = __builtin_amdgcn_mfma_f32_16x16x32_bf16(aq[3], c3, acc, 0, 0, 0);
        __builtin_amdgcn_s_setprio(0);
        const int coln = 7 * 16 + w * 2 + (l >> 3);
        #pragma unroll
        for (int r = 0; r < 4; ++r) {
            const int rr = quad * 4 + r;
            sc[rr][((coln ^ (rr & 7)) << 3) + (l & 7)] = f2bf(acc[r] * SCALE_F);
        }
    }
    __syncthreads();                                // all scores visible

    // ---- phase 2: regather + mask + max + normalize --------------------
    const int row = t >> 5, u = t & 31;             // 32 threads per row
    const int qg = qt * 16 + row;
    float x[32];
    #pragma unroll
    for (int c = 0; c < 4; ++c) {
        short8 v8 = *(const short8*)&sc[row][((c * 32 + u) ^ (row & 7)) << 3];
        #pragma unroll
        for (int e = 0; e < 8; ++e) x[c * 8 + e] = bf2f(((ushort*)&v8)[e]);
    }
    {   // mask: key = c*256 + u*8 + h*4 + e
        const int4* mrow = (const int4*)(M + ((size_t)b * S_ + qg) * S_);
        #pragma unroll
        for (int c = 0; c < 4; ++c) {
            #pragma unroll
            for (int h = 0; h < 2; ++h) {
                int4 mm = mrow[c * 64 + u * 2 + h];
                if (mm.x == 0) x[c * 8 + h * 4 + 0] = NEG_INF_F;
                if (mm.y == 0) x[c * 8 + h * 4 + 1] = NEG_INF_F;
                if (mm.z == 0) x[c * 8 + h * 4 + 2] = NEG_INF_F;
                if (mm.w == 0) x[c * 8 + h * 4 + 3] = NEG_INF_F;
            }
        }
    }
    float mx = -3.0e38f;
    #pragma unroll
    for (int j = 0; j < 32; ++j) mx = fmaxf(mx, x[j]);
    #pragma unroll
    for (int off = 1; off < 32; off <<= 1) mx = fmaxf(mx, __shfl_xor(mx, off));
    #pragma unroll
    for (int j = 0; j < 32; ++j) x[j] = (x[j] - mx) * 0.5f;   // x <= 0

    // ---- tau bisection on f(tau)=sum max(0,x-tau)^2=1, root in [-1,0] --
    // Full-register solve (handles all-masked rows: x==0 -> tau=-1/32).
    float lo = -1.f, hi = 0.f;
    #pragma unroll 1
    for (int it = 0; it < NITER; ++it) {
        const float tm = 0.5f * (lo + hi);
        float f = 0.f;
        #pragma unroll
        for (int j = 0; j < 32; ++j) {
            float d = fmaxf(x[j] - tm, 0.f);
            f = fmaf(d, d, f);
        }
        #pragma unroll
        for (int off = 1; off < 32; off <<= 1) f += __shfl_xor(f, off);
        const bool ge = (f >= 1.f);
        lo = ge ? tm : lo;
        hi = ge ? hi : tm;
    }
    const float tau = 0.5f * (lo + hi);

    // ---- y = max(0,x-tau)^2 back into sc (dense, swizzled) -------------
    #pragma unroll
    for (int c = 0; c < 4; ++c) {
        short8 v8;
        #pragma unroll
        for (int e = 0; e < 8; ++e) {
            float d = fmaxf(x[c * 8 + e] - tau, 0.f);
            ((ushort*)&v8)[e] = f2bf(d * d);
        }
        *(short8*)&sc[row][((c * 32 + u) ^ (row & 7)) << 3] = v8;
    }

    // V^T fragment base: d row = w*16+l; issue tile-0 loads pre-barrier
    const ushort* vp = vt_bh + (size_t)(w * 16 + l) * S_ + quad * 8;
    c0 = *(const short8*)(vp +  0);
    c1 = *(const short8*)(vp + 32);
    c2 = *(const short8*)(vp + 64);
    c3 = *(const short8*)(vp + 96);
    __syncthreads();                                // all y visible

    // ---- phase 3: O = P @ V^T, 8 key-tiles, barrier-free ---------------
    f32x4 oa = {0.f, 0.f, 0.f, 0.f};
    #pragma unroll 1
    for (int vt = 0; vt < 7; ++vt) {
        const ushort* np = vp + (size_t)(vt + 1) * 128;
        short8 n0 = *(const short8*)(np +  0);      // prefetch next tile
        short8 n1 = *(const short8*)(np + 32);
        short8 n2 = *(const short8*)(np + 64);
        short8 n3 = *(const short8*)(np + 96);
        short8 a0 = *(const short8*)&sc[l][((vt * 16 +  0 + quad) ^ (l & 7)) << 3];
        short8 a1 = *(const short8*)&sc[l][((vt * 16 +  4 + quad) ^ (l & 7)) << 3];
        short8 a2 = *(const short8*)&sc[l][((vt * 16 +  8 + quad) ^ (l & 7)) << 3];
        short8 a3 = *(const short8*)&sc[l][((vt * 16 + 12 + quad) ^ (l & 7)) << 3];
        __builtin_amdgcn_s_setprio(1);
        oa = __builtin_amdgcn_mfma_f32_16x16x32_bf16(a0, c0, oa, 0, 0, 0);
        oa = __builtin_amdgcn_mfma_f32_16x16x32_bf16(a1, c1, oa, 0, 0, 0);
        oa = __builtin_amdgcn_mfma_f32_16x16x32_bf16(a2, c2, oa, 0, 0, 0);
        oa = __builtin_amdgcn_mfma_f32_16x16x32_bf16(a3, c3, oa, 0, 0, 0);
        __builtin_amdgcn_s_setprio(0);
        c0 = n0; c1 = n1; c2 = n2; c3 = n3;
    }
    {   // vt = 7 (peeled)
        short8 a0 = *(const short8*)&sc[l][((7 * 16 +  0 + quad) ^ (l & 7)) << 3];
        short8 a1 = *(const short8*)&sc[l][((7 * 16 +  4 + quad) ^ (l & 7)) << 3];
        short8 a2 = *(const short8*)&sc[l][((7 * 16 +  8 + quad) ^ (l & 7)) << 3];
        short8 a3 = *(const short8*)&sc[l][((7 * 16 + 12 + quad) ^ (l & 7)) << 3];
        __builtin_amdgcn_s_setprio(1);
        oa = __builtin_amdgcn_mfma_f32_16x16x32_bf16(a0, c0, oa, 0, 0, 0);
        oa = __builtin_amdgcn_mfma_f32_16x16x32_bf16(a1, c1, oa, 0, 0, 0);
        oa = __builtin_amdgcn_mfma_f32_16x16x32_bf16(a2, c2, oa, 0, 0, 0);
        oa = __builtin_amdgcn_mfma_f32_16x16x32_bf16(a3, c3, oa, 0, 0, 0);
        __builtin_amdgcn_s_setprio(0);
    }

    // ---- epilogue: C/D map (col=d-within-slice=l, row=q=quad*4+r) ------
    float* ob = O + ((size_t)bh * S_ + (size_t)qt * 16) * D_;
    #pragma unroll
    for (int r = 0; r < 4; ++r)
        ob[(size_t)(quad * 4 + r) * D_ + w * 16 + l] = oa[r];
}

extern "C" void kernel_launch(void* const* d_in, const int* in_sizes, int n_in,
                              void* d_out, int out_size, void* d_ws, size_t ws_size,
                              hipStream_t stream) {
    const float* q = (const float*)d_in[0];
    const float* k = (const float*)d_in[1];
    const float* v = (const float*)d_in[2];
    const int*   m = (const int*)d_in[3];
    float*       o = (float*)d_out;

    ushort* Kb = (ushort*)d_ws;                      // 8,388,608 B
    ushort* Vt = (ushort*)((char*)d_ws + 8388608);   // 8,388,608 B

    pre_cvt<<<5120, 256, 0, stream>>>(k, v, Kb, Vt);
    entmax_attn<<<2048, 512, 0, stream>>>(q, Kb, Vt, m, o);
}